// Round 8
// baseline (503.694 us; speedup 1.0000x reference)
//
#include <hip/hip_runtime.h>
#include <hip/hip_fp16.h>
#include <hip/hip_cooperative_groups.h>
#include <math.h>

namespace cg = cooperative_groups;

#define N_NODES 100000
#define D_FEAT  128
#define E_EDGES 1600000
#define E2      (E_EDGES + N_NODES)   /* 1,700,000 with self-loops */
#define NEG_SLOPE 0.2f
#define LN_EPS    1e-5f

#define NB   391                      /* buckets of 256 nodes: d >> 8 */
#define TS   8192                     /* edges per tile */
#define NTIL ((E2 + TS - 1) / TS)     /* 208 */

typedef __attribute__((ext_vector_type(8))) short short8;
typedef __attribute__((ext_vector_type(4))) float floatx4;
typedef _Float16 h2 __attribute__((ext_vector_type(2)));   // packed half pair

static __device__ __forceinline__ float fdot2f(h2 a, h2 b, float c) {
#if __has_builtin(__builtin_amdgcn_fdot2)
    return __builtin_amdgcn_fdot2(a, b, c, false);
#else
    return (float)a[0] * (float)b[0] + (float)a[1] * (float)b[1] + c;
#endif
}

static __device__ __forceinline__ unsigned short f2bf(float f) {
    unsigned u = __float_as_uint(f);
    unsigned r = (u + 0x7fffu + ((u >> 16) & 1u)) >> 16;   // RNE
    return (unsigned short)r;
}

// ---------------------------------------------------------------------------
// Cooperative CSR build + weight prep, ONE kernel, zero global atomics.
//  A) per-tile LDS hist -> tcnt  (+ weight/att prep interleaved)
//  B) per-column (bucket) scan over tiles -> toff, bcnt   [wave per column]
//  C) bucket scan -> bstart; rowstart[N]=E2               [block 0]
//  D) deterministic tile scatter -> pairbuf (src | dstlow<<17)
//  E) per-bucket count+scan+scatter -> rowstart, csr_src  [blocks strided]
// ---------------------------------------------------------------------------
__global__ __launch_bounds__(1024) void csr_coop(
        const int* __restrict__ edge_src, const int* __restrict__ edge_dst,
        const float* __restrict__ Wl, const float* __restrict__ Wr,
        const float* __restrict__ att,
        unsigned short* __restrict__ Wt, _Float16* __restrict__ atth,
        int* __restrict__ tcnt, int* __restrict__ toff, int* __restrict__ bcnt,
        int* __restrict__ bstart, int* __restrict__ rowstart,
        unsigned* __restrict__ pairbuf, int* __restrict__ csr_src) {
    cg::grid_group grid = cg::this_grid();
    __shared__ int sA[512];
    __shared__ int sB[512];
    __shared__ int sC[512];
    const int t = threadIdx.x;
    const int blk = blockIdx.x;

    // ---- Phase A: tile histogram + weight prep ----
    if (t < NB) sA[t] = 0;
    __syncthreads();
    {
        const int base = blk * TS;
#pragma unroll
        for (int j = 0; j < TS / 1024; ++j) {
            int i = base + j * 1024 + t;
            if (i < E2) {
                int d = (i < E_EDGES) ? edge_dst[i] : (i - E_EDGES);
                atomicAdd(&sA[d >> 8], 1);
            }
        }
        // weight prep: Wt[(l*2+side)*16+kb][col][j] = W[l][k=kb*8+j][col] (bf16)
        int gid = blk * 1024 + t;
        for (int idx = gid; idx < 65536 + 256; idx += NTIL * 1024) {
            if (idx < 65536) {
                int l = idx >> 15, rem = idx & 32767, side = rem >> 14, cw = rem & 16383;
                int col = cw >> 7, k = cw & 127;
                const float* W = side ? Wr : Wl;
                int kb = k >> 3, j = k & 7;
                Wt[(size_t)((l * 2 + side) * 16 + kb) * 1024 + col * 8 + j] =
                    f2bf(W[l * 16384 + k * 128 + col]);
            } else {
                int j = idx - 65536;
                atth[j] = (_Float16)att[j];
            }
        }
    }
    __syncthreads();
    if (t < NB) tcnt[blk * NB + t] = sA[t];
    grid.sync();

    // ---- Phase B: per-column scan over tiles (wave per column) ----
    {
        int wv = (blk << 4) + (t >> 6);
        int lane = t & 63;
        if (wv < NB) {
            const int col = wv;
            int v[4]; int lsum = 0;
#pragma unroll
            for (int i = 0; i < 4; ++i) {
                int tt = lane * 4 + i;
                int x = (tt < NTIL) ? tcnt[tt * NB + col] : 0;
                v[i] = lsum; lsum += x;
            }
            int incl = lsum;
#pragma unroll
            for (int off = 1; off < 64; off <<= 1) {
                int x = __shfl_up(incl, off);
                if (lane >= off) incl += x;
            }
            int excl = incl - lsum;
#pragma unroll
            for (int i = 0; i < 4; ++i) {
                int tt = lane * 4 + i;
                if (tt < NTIL) toff[tt * NB + col] = excl + v[i];
            }
            if (lane == 63) bcnt[col] = incl;
        }
    }
    grid.sync();

    // ---- Phase C: bucket scan (block 0 only) ----
    if (blk == 0) {
        int v = (t < NB) ? bcnt[t] : 0;
        if (t < 512) sC[t] = v;
        __syncthreads();
        for (int off = 1; off < 512; off <<= 1) {
            int x = (t < 512 && t >= off) ? sC[t - off] : 0;
            __syncthreads();
            if (t < 512) sC[t] += x;
            __syncthreads();
        }
        if (t <= NB) bstart[t] = sC[t] - v;     // t==NB -> total == E2
        if (t == 0) rowstart[N_NODES] = E2;
    }
    grid.sync();

    // ---- Phase D: deterministic tile scatter ----
    {
        if (t < NB) { sA[t] = bstart[t] + toff[blk * NB + t]; sB[t] = 0; }
        __syncthreads();
        const int tb = blk * TS;
#pragma unroll
        for (int j = 0; j < TS / 1024; ++j) {
            int i = tb + j * 1024 + t;
            if (i < E2) {
                int d, sr;
                if (i < E_EDGES) { d = edge_dst[i]; sr = edge_src[i]; }
                else             { d = i - E_EDGES; sr = d; }
                int b = d >> 8;
                int rank = atomicAdd(&sB[b], 1);
                pairbuf[sA[b] + rank] = (unsigned)sr | ((unsigned)(d & 255) << 17);
            }
        }
    }
    grid.sync();

    // ---- Phase E: per-bucket fine sort ----
    for (int bk = blk; bk < NB; bk += NTIL) {
        if (t < 256) sA[t] = 0;
        __syncthreads();
        const int e0 = bstart[bk], e1 = bstart[bk + 1];
        for (int p = e0 + t; p < e1; p += 1024)
            atomicAdd(&sA[pairbuf[p] >> 17], 1);
        __syncthreads();
        int v = (t < 256) ? sA[t] : 0;
        if (t < 256) sB[t] = v;
        __syncthreads();
        for (int off = 1; off < 256; off <<= 1) {
            int x = (t < 256 && t >= off) ? sB[t - off] : 0;
            __syncthreads();
            if (t < 256) sB[t] += x;
            __syncthreads();
        }
        if (t < 256) {
            int excl = sB[t] - v;
            int node = (bk << 8) + t;
            if (node < N_NODES) rowstart[node] = e0 + excl;
            sC[t] = e0 + excl;
        }
        __syncthreads();
        for (int p = e0 + t; p < e1; p += 1024) {
            unsigned pr = pairbuf[p];
            int pos = atomicAdd(&sC[pr >> 17], 1);
            csr_src[pos] = (int)(pr & 0x1FFFF);
        }
        __syncthreads();
    }
}

// ---------------------------------------------------------------------------
// LDS-free MFMA GEMM: wave = 32 rows x 256 cols (Wl -> xl fp16, Wr -> xr fp16).
// Wt layout [side][kb][col][8]: a quad's 16 m-lanes read one contiguous 256B
// segment per B-frag load (coalesced; 4x fewer L2 line requests than [col][k]).
// Layer 0: A read directly from fp32 x (inline bf16 cvt); layer 1: bf16 hbf.
// ---------------------------------------------------------------------------
__global__ __launch_bounds__(256) void gemm_mfma2(
        const unsigned short* __restrict__ hbf,   // bf16 N x 128 (layer 1)
        const float* __restrict__ Afp,            // fp32 N x 128 (layer 0) or null
        const unsigned short* __restrict__ Wt,    // bf16 this layer, new layout
        _Float16* __restrict__ xl, _Float16* __restrict__ xr, int n_rows) {
    const int wave = threadIdx.x >> 6;
    const int lane = threadIdx.x & 63;
    const int m = lane & 15;
    const int q = lane >> 4;
    const int r0 = (blockIdx.x * 4 + wave) * 32;

    int arow0 = r0 + m;        if (arow0 >= n_rows) arow0 = n_rows - 1;
    int arow1 = r0 + 16 + m;   if (arow1 >= n_rows) arow1 = n_rows - 1;

    floatx4 acc[2][2][8];      // [side][rt][ct]
#pragma unroll
    for (int s = 0; s < 2; ++s)
#pragma unroll
        for (int rt = 0; rt < 2; ++rt)
#pragma unroll
            for (int ct = 0; ct < 8; ++ct) acc[s][rt][ct] = (floatx4){0.f,0.f,0.f,0.f};

#pragma unroll
    for (int ks = 0; ks < 4; ++ks) {
        const int k0 = ks * 32 + q * 8;
        short8 a0, a1;
        if (Afp) {
            float4 f0 = *(const float4*)(Afp + (size_t)arow0 * 128 + k0);
            float4 f1 = *(const float4*)(Afp + (size_t)arow0 * 128 + k0 + 4);
            float4 g0 = *(const float4*)(Afp + (size_t)arow1 * 128 + k0);
            float4 g1 = *(const float4*)(Afp + (size_t)arow1 * 128 + k0 + 4);
            a0 = (short8){(short)f2bf(f0.x), (short)f2bf(f0.y), (short)f2bf(f0.z), (short)f2bf(f0.w),
                          (short)f2bf(f1.x), (short)f2bf(f1.y), (short)f2bf(f1.z), (short)f2bf(f1.w)};
            a1 = (short8){(short)f2bf(g0.x), (short)f2bf(g0.y), (short)f2bf(g0.z), (short)f2bf(g0.w),
                          (short)f2bf(g1.x), (short)f2bf(g1.y), (short)f2bf(g1.z), (short)f2bf(g1.w)};
        } else {
            a0 = *(const short8*)(hbf + (size_t)arow0 * 128 + k0);
            a1 = *(const short8*)(hbf + (size_t)arow1 * 128 + k0);
        }
        const int kb = ks * 4 + q;
#pragma unroll
        for (int s = 0; s < 2; ++s) {
#pragma unroll
            for (int ct = 0; ct < 8; ++ct) {
                short8 b = *(const short8*)(Wt + (size_t)(s * 16 + kb) * 1024
                                            + (ct * 16 + m) * 8);
                acc[s][0][ct] = __builtin_amdgcn_mfma_f32_16x16x32_bf16(a0, b, acc[s][0][ct], 0, 0, 0);
                acc[s][1][ct] = __builtin_amdgcn_mfma_f32_16x16x32_bf16(a1, b, acc[s][1][ct], 0, 0, 0);
            }
        }
    }

#pragma unroll
    for (int s = 0; s < 2; ++s) {
        _Float16* out = s ? xr : xl;
#pragma unroll
        for (int rt = 0; rt < 2; ++rt)
#pragma unroll
            for (int ct = 0; ct < 8; ++ct)
#pragma unroll
                for (int i = 0; i < 4; ++i) {
                    int row = r0 + rt * 16 + q * 4 + i;
                    if (row < n_rows)
                        out[(size_t)row * 128 + ct * 16 + m] = (_Float16)acc[s][rt][ct][i];
                }
    }
}

// ---------------------------------------------------------------------------
// Fused per-node GATv2: edge-parallel lanes, packed fp16 math, 2-deep
// prefetch, shift-free softmax.  lacc/lS per-wave-disjoint -> no barriers.
// ---------------------------------------------------------------------------
union U16 { uint4 u; h2 h[4]; };

__global__ __launch_bounds__(256) void gat_node6(
        const _Float16* __restrict__ xl,          // fp16 N x 128
        const _Float16* __restrict__ xr,          // fp16 N x 128
        const float* __restrict__ h_in,
        const int* __restrict__ rowstart, const int* __restrict__ csr_src,
        const _Float16* __restrict__ atth, const float* __restrict__ bias,
        const float* __restrict__ gamma, const float* __restrict__ beta,
        float* __restrict__ h_out, unsigned* __restrict__ hbf_out) {
    __shared__ float lacc[4][8 * 136];
    __shared__ float lS[4][4];

    const int wave = threadIdx.x >> 6;
    const int lane = threadIdx.x & 63;
    const int node = blockIdx.x * 4 + wave;       // grid exact: 25000*4
    const int esub = lane >> 3;
    const int r    = lane & 7;
    const int c0   = r * 16;

    U16 xra, xrb, ata, atb;
    {
        const uint4* xp = (const uint4*)(xr + (size_t)node * 128 + c0);
        xra.u = xp[0]; xrb.u = xp[1];
        const uint4* ap = (const uint4*)(atth + c0);
        ata.u = ap[0]; atb.u = ap[1];
    }
    const h2 ns2 = {(_Float16)NEG_SLOPE, (_Float16)NEG_SLOPE};

    const int p0 = rowstart[node], p1 = rowstart[node + 1];
    float s = 0.f;
    h2 acc2[8];
#pragma unroll
    for (int j = 0; j < 8; ++j) acc2[j] = (h2){(_Float16)0.f, (_Float16)0.f};

    const unsigned short* xls = (const unsigned short*)xl;

    int pb = p0;
    bool vA = (p0 + esub) < p1;
    U16 a0, a1, b0, b1;
    {
        int pc = vA ? (p0 + esub) : (p1 - 1);
        int src = csr_src[pc];
        const uint4* rp = (const uint4*)(xls + (size_t)src * 128 + c0);
        a0.u = rp[0]; a1.u = rp[1];
    }
    bool vB = false;
    if (p0 + 8 < p1) {
        vB = (p0 + 8 + esub) < p1;
        int pc = vB ? (p0 + 8 + esub) : (p1 - 1);
        int src = csr_src[pc];
        const uint4* rp = (const uint4*)(xls + (size_t)src * 128 + c0);
        b0.u = rp[0]; b1.u = rp[1];
    }

    while (pb < p1) {
        U16 c0v, c1v;
        bool vC = false;
        if (pb + 16 < p1) {                        // wave-uniform
            vC = (pb + 16 + esub) < p1;
            int pc = vC ? (pb + 16 + esub) : (p1 - 1);
            int src = csr_src[pc];
            const uint4* rp = (const uint4*)(xls + (size_t)src * 128 + c0);
            c0v.u = rp[0]; c1v.u = rp[1];
        }

        float d = 0.f;
#pragma unroll
        for (int qq = 0; qq < 4; ++qq) {
            h2 z  = a0.h[qq] + xra.h[qq];
            h2 lk = __builtin_elementwise_max(z, z * ns2);
            d = fdot2f(lk, ata.h[qq], d);
        }
#pragma unroll
        for (int qq = 0; qq < 4; ++qq) {
            h2 z  = a1.h[qq] + xrb.h[qq];
            h2 lk = __builtin_elementwise_max(z, z * ns2);
            d = fdot2f(lk, atb.h[qq], d);
        }
        float alpha = d + __shfl_xor(d, 1);
        float w = vA ? __expf(alpha) : 0.f;
        s += w;
        h2 w2 = {(_Float16)w, (_Float16)w};
#pragma unroll
        for (int qq = 0; qq < 4; ++qq)
            acc2[qq] = w2 * a0.h[qq] + acc2[qq];
#pragma unroll
        for (int qq = 0; qq < 4; ++qq)
            acc2[qq + 4] = w2 * a1.h[qq] + acc2[qq + 4];

        a0 = b0; a1 = b1; vA = vB;
        b0 = c0v; b1 = c1v; vB = vC;
        pb += 8;
    }

    float ssum = s;
    ssum += __shfl_xor(ssum, 8);
    ssum += __shfl_xor(ssum, 16);
    ssum += __shfl_xor(ssum, 32);

    float* lb = &lacc[wave][esub * 136 + c0];
#pragma unroll
    for (int qq = 0; qq < 4; ++qq) {
        h2 lo = acc2[2 * qq], hi = acc2[2 * qq + 1];
        float4 o = {(float)lo[0], (float)lo[1], (float)hi[0], (float)hi[1]};
        *(float4*)(lb + 4 * qq) = o;
    }
    if (esub == 0 && (r & 1) == 0) lS[wave][r >> 1] = ssum;
    // no barrier: all lacc/lS traffic is wave-local (ordered by lgkmcnt)

    const int c = lane * 2;
    float S = lS[wave][lane >> 4];
    float g0 = 0.f, g1 = 0.f;
#pragma unroll
    for (int e = 0; e < 8; ++e) {
        float2 f = *(const float2*)(&lacc[wave][e * 136 + c]);
        g0 += f.x; g1 += f.y;
    }
    const float invS = 1.f / S;
    g0 = g0 * invS + bias[c];
    g1 = g1 * invS + bias[c + 1];

    float sum = g0 + g1, sq = g0 * g0 + g1 * g1;
#pragma unroll
    for (int off = 1; off < 64; off <<= 1) {
        sum += __shfl_xor(sum, off);
        sq  += __shfl_xor(sq, off);
    }
    float mu   = sum * (1.f / 128.f);
    float var  = sq * (1.f / 128.f) - mu * mu;
    float rstd = rsqrtf(var + LN_EPS);
    float y0 = (g0 - mu) * rstd * gamma[c]     + beta[c];
    float y1 = (g1 - mu) * rstd * gamma[c + 1] + beta[c + 1];
    float e0 = (y0 > 0.f) ? y0 : (__expf(y0) - 1.f);
    float e1 = (y1 > 0.f) ? y1 : (__expf(y1) - 1.f);

    const float2 hv = *(const float2*)(h_in + (size_t)node * 128 + c);
    float2 o;
    o.x = hv.x + e0;
    o.y = hv.y + e1;
    *(float2*)(h_out + (size_t)node * 128 + c) = o;
    if (hbf_out) {                                // layer 0: bf16 copy for next GEMM
        unsigned pk = (unsigned)f2bf(o.x) | ((unsigned)f2bf(o.y) << 16);
        hbf_out[(size_t)node * 64 + lane] = pk;
    }
}

// ---------------------------------------------------------------------------
extern "C" void kernel_launch(void* const* d_in, const int* in_sizes, int n_in,
                              void* d_out, int out_size, void* d_ws, size_t ws_size,
                              hipStream_t stream) {
    const float* x     = (const float*)d_in[0];
    const int*   eidx  = (const int*)d_in[1];   // (2, E)
    const float* Wl    = (const float*)d_in[2]; // (L,128,128)
    const float* Wr    = (const float*)d_in[3];
    const float* att   = (const float*)d_in[4]; // (L,4,32) -> stride 128
    const float* bias  = (const float*)d_in[5];
    const float* gamma = (const float*)d_in[6];
    const float* beta  = (const float*)d_in[7];
    float* out = (float*)d_out;

    char* ws = (char*)d_ws;
    _Float16* xl = (_Float16*)ws;              ws += (size_t)N_NODES * 128 * 2;
    _Float16* xr = (_Float16*)ws;              ws += (size_t)N_NODES * 128 * 2;
    float* h1 = (float*)ws;                    ws += (size_t)N_NODES * 128 * 4;
    unsigned short* hbf = (unsigned short*)ws; ws += (size_t)N_NODES * 128 * 2;
    unsigned short* Wt  = (unsigned short*)ws; ws += (size_t)65536 * 2;
    _Float16* atth = (_Float16*)ws;            ws += 256 * 2;
    unsigned* pairbuf = (unsigned*)ws;         ws += (size_t)E2 * 4;
    int* tcnt     = (int*)ws; ws += (size_t)NTIL * NB * 4;
    int* toff     = (int*)ws; ws += (size_t)NTIL * NB * 4;
    int* bcnt     = (int*)ws; ws += (NB + 1) * 4;
    int* bstart   = (int*)ws; ws += (NB + 1) * 4;
    int* rowstart = (int*)ws; ws += (size_t)(N_NODES + 4) * 4;
    int* csr_src  = (int*)ws; ws += (size_t)E2 * 4;

    const int* edge_src = eidx;
    const int* edge_dst = eidx + E_EDGES;

    // ---- fused CSR build + weight prep (single cooperative launch) ----
    {
        void* args[] = {(void*)&edge_src, (void*)&edge_dst, (void*)&Wl, (void*)&Wr,
                        (void*)&att, (void*)&Wt, (void*)&atth, (void*)&tcnt,
                        (void*)&toff, (void*)&bcnt, (void*)&bstart, (void*)&rowstart,
                        (void*)&pairbuf, (void*)&csr_src};
        (void)hipLaunchCooperativeKernel((void*)csr_coop, dim3(NTIL), dim3(1024),
                                         args, 0, stream);
    }

    // ---- two GATv2 layers ----
    const int gemm_gx = (N_NODES + 127) / 128;   // 782
    for (int l = 0; l < 2; ++l) {
        const float* hin  = (l == 0) ? x  : h1;
        float*       hout = (l == 1) ? out : h1;
        gemm_mfma2<<<gemm_gx, 256, 0, stream>>>(
            hbf, (l == 0) ? x : nullptr, Wt + (size_t)l * 32768, xl, xr, N_NODES);
        gat_node6<<<N_NODES / 4, 256, 0, stream>>>(
            xl, xr, hin, rowstart, csr_src,
            atth + l * 128, bias + l * 128, gamma + l * 128, beta + l * 128,
            hout, (l == 0) ? (unsigned*)hbf : nullptr);
    }
}